// Round 2
// baseline (812.004 us; speedup 1.0000x reference)
//
#include <hip/hip_runtime.h>

// VQ nearest-codebook: N=262144 rows x D=64, K=1024 codes.
// Numerics contract (bit-exact vs np f32 reference, verified in prior session):
//   dist_k = fl32( fl32(zsq - 2*dot_k) + cbsq_k ), argmin -> lowest index wins.
//   dot_k MUST be one sequential fmaf chain d=0..63 per row. DO NOT re-associate.
//   zsq/cbsq: f64-accumulate then round once.
//
// R5 change: SGPR codebook loads (s_load_dwordx16) + half-row software pipeline.
//   Rationale (rocprof r4): VALU-issue time 272us ~ 218us FMA floor, but wall
//   585us -> 54% memory-stall. The c-row address is wave-uniform; vector loads
//   of it waste the TA path (4cyc/wave64 VMEM inst, CU-shared) and 64 VGPRs,
//   and same-register reuse forces a full load-latency stall every iteration.
//   Fix: force scalar loads via inline asm (hipcc never scalarizes this),
//   half-row (32-float) depth-1 pipeline with wait-before-issue (SMEM returns
//   out-of-order -> only lgkmcnt(0) waits are safe). VGPR drops to ~90 ->
//   R=1 rows/thread and the grid's full 4 waves/SIMD (4096 waves/1024 SIMDs).
//   Latency budget per half-row = 32 FMAs x 2cyc x 4 waves ~ 256 cyc >= L2.
//   Rule-#18 guard: the waitcnt asm takes the buffers AND the accumulator as
//   in/outs so FMAs cannot be scheduled across it.

#define VQ_D 64
#define VQ_MAXK 1024

typedef __attribute__((ext_vector_type(16))) float f32x16;

// Issue scalar loads for half A (floats 0..31) / half B (floats 32..63) of the
// 256-byte row at ptr. Early-clobber: dst must not alias the address pair.
#define VQ_SLOAD_A(bL, bH, ptr) \
    asm volatile("s_load_dwordx16 %0, %2, 0x0\n\t" \
                 "s_load_dwordx16 %1, %2, 0x40" \
                 : "=&s"(bL), "=&s"(bH) : "s"(ptr))
#define VQ_SLOAD_B(bL, bH, ptr) \
    asm volatile("s_load_dwordx16 %0, %2, 0x80\n\t" \
                 "s_load_dwordx16 %1, %2, 0xC0" \
                 : "=&s"(bL), "=&s"(bH) : "s"(ptr))

// Wait for outstanding scalar loads. In/outs the buffers (consumers must read
// post-wait values) and the accumulator (prior FMAs cannot sink below, later
// FMAs cannot hoist above — rule #18).
#define VQ_SWAIT(bL, bH, acc) \
    asm volatile("s_waitcnt lgkmcnt(0)" \
                 : "+s"(bL), "+s"(bH), "+v"(acc) :: "memory")

// Sequential fused-FMA chain over one float4 of z against 4 consecutive
// codebook floats (compile-time lane index j into an f32x16). Ascending d.
#define VQ_CHV(q, cv, j) do { \
    s = fmaf((q).x, (cv)[(j)+0], s); \
    s = fmaf((q).y, (cv)[(j)+1], s); \
    s = fmaf((q).z, (cv)[(j)+2], s); \
    s = fmaf((q).w, (cv)[(j)+3], s); } while (0)

// f64 sum-of-squares over one float4 (order-free: tie-invariant).
#define VQ_SQ(q) do { \
    zsqd += (double)(q).x * (double)(q).x; \
    zsqd += (double)(q).y * (double)(q).y; \
    zsqd += (double)(q).z * (double)(q).z; \
    zsqd += (double)(q).w * (double)(q).w; } while (0)

__global__ __launch_bounds__(256, 4) void vq_argmin_kernel(
    const float* __restrict__ z_e,
    const float* __restrict__ cb,
    float* __restrict__ out,   // [N*D] z_q, then [N] indices (as float)
    int N, int K)
{
    __shared__ float s_cbsq[VQ_MAXK];

    // cb_sq per code: f64 accumulate, round once to f32. (Verified numerics —
    // do not change.)
    for (int k = threadIdx.x; k < K; k += blockDim.x) {
        const float* c = cb + (size_t)k * VQ_D;
        double s = 0.0;
        #pragma unroll
        for (int d = 0; d < VQ_D; ++d) { double v = (double)c[d]; s += v * v; }
        s_cbsq[k] = (float)s;
    }
    __syncthreads();

    const int n = blockIdx.x * blockDim.x + threadIdx.x;
    if (n >= N) return;

    // z row in 16 named float4 registers (NOT an array — scratch hazard).
    const float4* zp = (const float4*)(z_e + (size_t)n * VQ_D);
    float4 q0  = zp[0],  q1  = zp[1],  q2  = zp[2],  q3  = zp[3];
    float4 q4  = zp[4],  q5  = zp[5],  q6  = zp[6],  q7  = zp[7];
    float4 q8  = zp[8],  q9  = zp[9],  q10 = zp[10], q11 = zp[11];
    float4 q12 = zp[12], q13 = zp[13], q14 = zp[14], q15 = zp[15];

    // ||z||^2 in f64, rounded once.
    double zsqd = 0.0;
    VQ_SQ(q0);  VQ_SQ(q1);  VQ_SQ(q2);  VQ_SQ(q3);
    VQ_SQ(q4);  VQ_SQ(q5);  VQ_SQ(q6);  VQ_SQ(q7);
    VQ_SQ(q8);  VQ_SQ(q9);  VQ_SQ(q10); VQ_SQ(q11);
    VQ_SQ(q12); VQ_SQ(q13); VQ_SQ(q14); VQ_SQ(q15);
    const float zsq = (float)zsqd;

    float best = 3.4e38f;
    int bestk = 0;

    // Pipeline state: bufA* = current row's half A (d0..31), bufB* = half B.
    // Entry invariant each iteration: A(k) ready in regs, B(k) in flight.
    f32x16 bufAL, bufAH, bufBL, bufBH;
    {
        const float* cp0 = cb;  // row 0 (wave-uniform address)
        VQ_SLOAD_A(bufAL, bufAH, cp0);
        asm volatile("s_waitcnt lgkmcnt(0)"
                     : "+s"(bufAL), "+s"(bufAH) :: "memory");
        VQ_SLOAD_B(bufBL, bufBH, cp0);
    }

    #pragma unroll 1
    for (int k = 0; k < K; ++k) {
        float s = 0.f;

        // FMA half A (d0..31) while B(k) is in flight. Ascending d.
        VQ_CHV(q0, bufAL, 0);  VQ_CHV(q1, bufAL, 4);
        VQ_CHV(q2, bufAL, 8);  VQ_CHV(q3, bufAL, 12);
        VQ_CHV(q4, bufAH, 0);  VQ_CHV(q5, bufAH, 4);
        VQ_CHV(q6, bufAH, 8);  VQ_CHV(q7, bufAH, 12);

        const float cq = s_cbsq[k];       // ds_read; drained by the next wait

        VQ_SWAIT(bufBL, bufBH, s);        // B(k) ready (pins after A-FMAs)

        // Next row pointer (clamped: avoids both a per-iter branch and an
        // out-of-bounds prefetch on the last iteration).
        int nk = k + 1; if (nk >= K) nk = K - 1;
        const float* np = cb + (size_t)nk * VQ_D;
        VQ_SLOAD_A(bufAL, bufAH, np);     // A(k+1) in flight under B-FMAs

        // FMA half B (d32..63). Ascending d, same sequential chain.
        VQ_CHV(q8,  bufBL, 0);  VQ_CHV(q9,  bufBL, 4);
        VQ_CHV(q10, bufBL, 8);  VQ_CHV(q11, bufBL, 12);
        VQ_CHV(q12, bufBH, 0);  VQ_CHV(q13, bufBH, 4);
        VQ_CHV(q14, bufBH, 8);  VQ_CHV(q15, bufBH, 12);

        const float u    = zsq - 2.0f * s;   // fp32 round, as reference
        const float dist = u + cq;           // fp32 round, as reference
        if (dist < best) { best = dist; bestk = k; }  // strict <: lowest k wins

        VQ_SWAIT(bufAL, bufAH, s);        // A(k+1) ready
        VQ_SLOAD_B(bufBL, bufBH, np);     // B(k+1) in flight under next A-FMAs
    }

    // Drain the dangling B(K-1)-duplicate prefetch before its SGPRs can be
    // reused by the epilogue (pending s_load writing recycled regs = corruption).
    asm volatile("s_waitcnt lgkmcnt(0)" ::: "memory");

    // z_q gather (codebook L2/L3-resident), float4 stores.
    const float4* cq4 = (const float4*)(cb + (size_t)bestk * VQ_D);
    float4* oq = (float4*)(out + (size_t)n * VQ_D);
    #pragma unroll
    for (int i = 0; i < VQ_D / 4; ++i) oq[i] = cq4[i];

    // Index as float (exact for k < 2^24).
    out[(size_t)N * VQ_D + n] = (float)bestk;
}

extern "C" void kernel_launch(void* const* d_in, const int* in_sizes, int n_in,
                              void* d_out, int out_size, void* d_ws, size_t ws_size,
                              hipStream_t stream) {
    const float* z_e = (const float*)d_in[0];
    const float* cb  = (const float*)d_in[1];
    float* out = (float*)d_out;

    const int N = in_sizes[0] / VQ_D;
    const int K = in_sizes[1] / VQ_D;

    const int block = 256;
    const int grid = (N + block - 1) / block;
    vq_argmin_kernel<<<grid, block, 0, stream>>>(z_e, cb, out, N, K);
}

// Round 3
// 586.675 us; speedup vs baseline: 1.3841x; 1.3841x over previous
//
#include <hip/hip_runtime.h>

// VQ nearest-codebook: N=262144 rows x D=64, K=1024 codes.
// Numerics contract (bit-exact vs np f32 reference, verified in prior session):
//   dist_k = fl32( fl32(zsq - 2*dot_k) + cbsq_k ), argmin -> lowest index wins.
//   dot_k MUST be one sequential fmaf chain d=0..63 per row. DO NOT re-associate.
//   zsq/cbsq: f64-accumulate then round once. Codebook values pass through LDS
//   unchanged -> bit-exact.
//
// R6 change: LDS-staged codebook tiles (64 rows, double-buffered) + R=2.
//   Rationale: R4 showed VALU-issue 272us ~ FMA floor 218us but 54% wall
//   stalled on codebook load latency (~400-600cyc effective, c-regs reused
//   every iter, only 2 waves/SIMD to hide it). R5's SGPR-asm pipeline spilled
//   (WRITE_SIZE 67->181MB) -- allocator fallout, abandoned.
//   Fix: stage tiles via coalesced per-lane loads prefetched one FULL tile
//   (64 rows) ahead -> ~16k-cycle latency window, 1 barrier/tile. Inner loop
//   reads c from LDS at wave-uniform addresses = broadcast, conflict-free,
//   ~120cyc, fully hidden by 2 waves under 256 FMA-issue cyc/row.
//   Budget/row/wave ~283 cyc -> ~242us predicted.
//   VGPR audit: q 128 + c 64 + prefetch 16 + misc ~20 = ~230 < 256 (2 w/SIMD).
//   NO per-thread arrays anywhere (scratch hazard) -- all named float4s.

#define VQ_D 64
#define VQ_MAXK 1024
#define TILE_ROWS 64
#define TILE_F4 (TILE_ROWS * (VQ_D / 4))   // 1024 float4 = 16 KB per buffer

// Two-row sequential fused-FMA chain step over one float4 (ascending d within
// each row's chain; chains independent -> ILP without reassociation).
#define VQ_CH2(qa, qb, c) do { \
    s0 = fmaf((qa).x, (c).x, s0); s1 = fmaf((qb).x, (c).x, s1); \
    s0 = fmaf((qa).y, (c).y, s0); s1 = fmaf((qb).y, (c).y, s1); \
    s0 = fmaf((qa).z, (c).z, s0); s1 = fmaf((qb).z, (c).z, s1); \
    s0 = fmaf((qa).w, (c).w, s0); s1 = fmaf((qb).w, (c).w, s1); } while (0)

// f64 sum-of-squares over one float4 (order-free: tie-invariant).
#define VQ_SQ(acc, q) do { \
    (acc) += (double)(q).x * (double)(q).x; \
    (acc) += (double)(q).y * (double)(q).y; \
    (acc) += (double)(q).z * (double)(q).z; \
    (acc) += (double)(q).w * (double)(q).w; } while (0)

__global__ __launch_bounds__(256, 2) void vq_argmin_kernel(
    const float* __restrict__ z_e,
    const float* __restrict__ cb,
    float* __restrict__ out,   // [N*D] z_q, then [N] indices (as float)
    int N, int K)
{
    __shared__ float  s_cbsq[VQ_MAXK];          // 4 KB
    __shared__ float4 s_tile[2][TILE_F4];       // 32 KB double-buffered tile

    const int tid = threadIdx.x;

    // cb_sq per code: f64 accumulate, round once to f32. (Verified numerics —
    // do not change.)
    for (int k = tid; k < K; k += blockDim.x) {
        const float* c = cb + (size_t)k * VQ_D;
        double s = 0.0;
        #pragma unroll
        for (int d = 0; d < VQ_D; ++d) { double v = (double)c[d]; s += v * v; }
        s_cbsq[k] = (float)s;
    }

    // Two rows per thread: n0 = b*512 + t, n1 = n0 + 256. Clamp (not return!)
    // for generic N — every thread must reach the barriers.
    int n0 = blockIdx.x * (2 * (int)blockDim.x) + tid;
    const bool v0 = (n0 < N);
    if (!v0) n0 = N - 1;
    int n1 = n0 + (int)blockDim.x;
    const bool v1 = (n1 < N);
    if (!v1) n1 = n0;

    // Both z rows in 32 NAMED float4 registers (NOT arrays — scratch hazard).
    const float4* zp0 = (const float4*)(z_e + (size_t)n0 * VQ_D);
    const float4* zp1 = (const float4*)(z_e + (size_t)n1 * VQ_D);
    float4 a0  = zp0[0],  a1  = zp0[1],  a2  = zp0[2],  a3  = zp0[3];
    float4 a4  = zp0[4],  a5  = zp0[5],  a6  = zp0[6],  a7  = zp0[7];
    float4 a8  = zp0[8],  a9  = zp0[9],  a10 = zp0[10], a11 = zp0[11];
    float4 a12 = zp0[12], a13 = zp0[13], a14 = zp0[14], a15 = zp0[15];
    float4 b0  = zp1[0],  b1  = zp1[1],  b2  = zp1[2],  b3  = zp1[3];
    float4 b4  = zp1[4],  b5  = zp1[5],  b6  = zp1[6],  b7  = zp1[7];
    float4 b8  = zp1[8],  b9  = zp1[9],  b10 = zp1[10], b11 = zp1[11];
    float4 b12 = zp1[12], b13 = zp1[13], b14 = zp1[14], b15 = zp1[15];

    // ||z||^2 in f64, rounded once (per row).
    double zs0 = 0.0, zs1 = 0.0;
    VQ_SQ(zs0, a0);  VQ_SQ(zs0, a1);  VQ_SQ(zs0, a2);  VQ_SQ(zs0, a3);
    VQ_SQ(zs0, a4);  VQ_SQ(zs0, a5);  VQ_SQ(zs0, a6);  VQ_SQ(zs0, a7);
    VQ_SQ(zs0, a8);  VQ_SQ(zs0, a9);  VQ_SQ(zs0, a10); VQ_SQ(zs0, a11);
    VQ_SQ(zs0, a12); VQ_SQ(zs0, a13); VQ_SQ(zs0, a14); VQ_SQ(zs0, a15);
    VQ_SQ(zs1, b0);  VQ_SQ(zs1, b1);  VQ_SQ(zs1, b2);  VQ_SQ(zs1, b3);
    VQ_SQ(zs1, b4);  VQ_SQ(zs1, b5);  VQ_SQ(zs1, b6);  VQ_SQ(zs1, b7);
    VQ_SQ(zs1, b8);  VQ_SQ(zs1, b9);  VQ_SQ(zs1, b10); VQ_SQ(zs1, b11);
    VQ_SQ(zs1, b12); VQ_SQ(zs1, b13); VQ_SQ(zs1, b14); VQ_SQ(zs1, b15);
    const float zsq0 = (float)zs0;
    const float zsq1 = (float)zs1;

    // Stage tile 0 (coalesced: 256 threads x 4 float4 = 16 KB).
    const float4* cb4 = (const float4*)cb;
    {
        float4 t0 = cb4[tid],       t1 = cb4[tid + 256];
        float4 t2 = cb4[tid + 512], t3 = cb4[tid + 768];
        s_tile[0][tid]       = t0;  s_tile[0][tid + 256] = t1;
        s_tile[0][tid + 512] = t2;  s_tile[0][tid + 768] = t3;
    }
    __syncthreads();   // covers s_cbsq too

    float best0 = 3.4e38f, best1 = 3.4e38f;
    int bk0 = 0, bk1 = 0;

    const int NT = K / TILE_ROWS;   // 16 tiles
    int cur = 0;

    #pragma unroll 1
    for (int t = 0; t < NT; ++t) {
        // Prefetch tile t+1 into regs (clamped: last iter reloads tile t —
        // harmless, avoids OOB). Latency window = entire 64-row FMA loop.
        const int tn = (t + 1 < NT) ? (t + 1) : t;
        const float4* gp = cb4 + (size_t)tn * TILE_F4;
        float4 t0 = gp[tid],       t1 = gp[tid + 256];
        float4 t2 = gp[tid + 512], t3 = gp[tid + 768];

        const float4* lt = &s_tile[cur][0];
        const int kbase = t * TILE_ROWS;

        #pragma unroll 1
        for (int r = 0; r < TILE_ROWS; ++r) {
            const float4* rp = lt + (r << 4);   // wave-uniform -> LDS broadcast
            float s0 = 0.f, s1 = 0.f;

            // Half A (d0..31): 8 broadcast ds_reads, then 64 FMAs.
            float4 c0 = rp[0], c1 = rp[1], c2 = rp[2], c3 = rp[3];
            float4 c4 = rp[4], c5 = rp[5], c6 = rp[6], c7 = rp[7];
            VQ_CH2(a0, b0, c0); VQ_CH2(a1, b1, c1);
            VQ_CH2(a2, b2, c2); VQ_CH2(a3, b3, c3);
            VQ_CH2(a4, b4, c4); VQ_CH2(a5, b5, c5);
            VQ_CH2(a6, b6, c6); VQ_CH2(a7, b7, c7);

            // Half B (d32..63): separate names so reads can hoist above A-FMAs.
            float4 d0 = rp[8],  d1 = rp[9],  d2 = rp[10], d3 = rp[11];
            float4 d4 = rp[12], d5 = rp[13], d6 = rp[14], d7 = rp[15];
            VQ_CH2(a8,  b8,  d0); VQ_CH2(a9,  b9,  d1);
            VQ_CH2(a10, b10, d2); VQ_CH2(a11, b11, d3);
            VQ_CH2(a12, b12, d4); VQ_CH2(a13, b13, d5);
            VQ_CH2(a14, b14, d6); VQ_CH2(a15, b15, d7);

            const int k = kbase + r;
            const float cq = s_cbsq[k];
            const float u0    = zsq0 - 2.0f * s0;   // fp32 round, as reference
            const float dist0 = u0 + cq;            // fp32 round, as reference
            const float u1    = zsq1 - 2.0f * s1;
            const float dist1 = u1 + cq;
            if (dist0 < best0) { best0 = dist0; bk0 = k; }  // strict <
            if (dist1 < best1) { best1 = dist1; bk1 = k; }
        }

        // Write prefetched tile into the other buffer (auto vmcnt wait here),
        // one barrier per tile. Reads of that buffer ended before the PREVIOUS
        // barrier, so write-after-read is safe.
        s_tile[cur ^ 1][tid]       = t0;  s_tile[cur ^ 1][tid + 256] = t1;
        s_tile[cur ^ 1][tid + 512] = t2;  s_tile[cur ^ 1][tid + 768] = t3;
        __syncthreads();
        cur ^= 1;
    }

    // z_q gathers (codebook L2-resident), float4 stores.
    if (v0) {
        const float4* cq0 = (const float4*)(cb + (size_t)bk0 * VQ_D);
        float4* oq0 = (float4*)(out + (size_t)n0 * VQ_D);
        #pragma unroll
        for (int i = 0; i < VQ_D / 4; ++i) oq0[i] = cq0[i];
        out[(size_t)N * VQ_D + n0] = (float)bk0;
    }
    if (v1) {
        const float4* cq1 = (const float4*)(cb + (size_t)bk1 * VQ_D);
        float4* oq1 = (float4*)(out + (size_t)n1 * VQ_D);
        #pragma unroll
        for (int i = 0; i < VQ_D / 4; ++i) oq1[i] = cq1[i];
        out[(size_t)N * VQ_D + n1] = (float)bk1;
    }
}

extern "C" void kernel_launch(void* const* d_in, const int* in_sizes, int n_in,
                              void* d_out, int out_size, void* d_ws, size_t ws_size,
                              hipStream_t stream) {
    const float* z_e = (const float*)d_in[0];
    const float* cb  = (const float*)d_in[1];
    float* out = (float*)d_out;

    const int N = in_sizes[0] / VQ_D;
    const int K = in_sizes[1] / VQ_D;

    const int block = 256;
    const int rows_per_block = 2 * block;
    const int grid = (N + rows_per_block - 1) / rows_per_block;
    vq_argmin_kernel<<<grid, block, 0, stream>>>(z_e, cb, out, N, K);
}

// Round 4
// 584.148 us; speedup vs baseline: 1.3901x; 1.0043x over previous
//
#include <hip/hip_runtime.h>

// VQ nearest-codebook: N=262144 rows x D=64, K=1024 codes.
// Numerics contract (bit-exact vs np f32 reference, verified in prior session):
//   dist_k = fl32( fl32(zsq - 2*dot_k) + cbsq_k ), argmin -> lowest index wins.
//   dot_k MUST be one sequential fmaf chain d=0..63 per row. DO NOT re-associate.
//   zsq/cbsq: f64-accumulate then round once. (2*s is exact; fp-contract of
//   zsq-2*s to fma(-2,s,zsq) is value-identical.)
//
// R7 change: SGPR codebook via address-space(4) loads (compiler-managed).
//   Rationale (R6 counters): wall 1336 cyc/row-iter/CU vs 552 cyc VALU work.
//   Gap = LDS return path: broadcast ds_read_b128 writes 16B x 64 lanes = 1KB
//   VGPR traffic each (8 waves x 16 reads/row ~ 1024+ cyc/row). R4's global
//   vector loads measured the same (1370) -> ANY per-lane materialization of
//   the wave-uniform row pays 64x replication. Fix: constant-AS loads select
//   to s_load_dwordxN (SMEM pipe, no replication); v_fmac reads the SGPR
//   operand directly. R5 tried this with inline asm and died on regalloc;
//   here the compiler owns allocation/waitcnt/WAW.
//   SMEM returns OUT-OF-ORDER -> any dependent use = lgkmcnt(0) draining all.
//   So: half-row ping-pong (X,Y; 32 SGPR each), issue clusters boxed with
//   sched_barrier(0) placed AFTER the first consuming FMA of the other
//   buffer, giving ~450+ wave-cyc issue->drain distance (covers scalar-L2).
//   cbsq precomputed to workspace by kernel1 -> s_load too (LDS-free loop);
//   falls back to LDS cbsq if no workspace.
//   NO per-thread arrays anywhere (scratch hazard) -- all named values.

#define VQ_D 64
#define VQ_MAXK 1024

typedef __attribute__((ext_vector_type(4))) float f4;
typedef const __attribute__((address_space(4))) f4* cb4c_t;
typedef const __attribute__((address_space(4))) float* fc_t;

// Two-row sequential fused-FMA chain step over one float4-worth of c
// (ascending d within each row's chain; chains independent -> ILP without
// reassociation). c may be an SGPR-resident f4.
#define VQ_CH2(qa, qb, c) do { \
    s0 = fmaf((qa).x, (c).x, s0); s1 = fmaf((qb).x, (c).x, s1); \
    s0 = fmaf((qa).y, (c).y, s0); s1 = fmaf((qb).y, (c).y, s1); \
    s0 = fmaf((qa).z, (c).z, s0); s1 = fmaf((qb).z, (c).z, s1); \
    s0 = fmaf((qa).w, (c).w, s0); s1 = fmaf((qb).w, (c).w, s1); } while (0)

// f64 sum-of-squares over one float4 (order-free: tie-invariant).
#define VQ_SQ(acc, q) do { \
    (acc) += (double)(q).x * (double)(q).x; \
    (acc) += (double)(q).y * (double)(q).y; \
    (acc) += (double)(q).z * (double)(q).z; \
    (acc) += (double)(q).w * (double)(q).w; } while (0)

#define SBAR() __builtin_amdgcn_sched_barrier(0)

// kernel1: cbsq[k] = fl32(sum_d f64(cb[k][d]^2)). Same numerics as the old
// in-block prologue (f64 accumulate, round once).
__global__ void vq_cbsq_kernel(const float* __restrict__ cb,
                               float* __restrict__ cbsq, int K)
{
    const int k = blockIdx.x * blockDim.x + threadIdx.x;
    if (k >= K) return;
    const float* c = cb + (size_t)k * VQ_D;
    double s = 0.0;
    #pragma unroll
    for (int d = 0; d < VQ_D; ++d) { double v = (double)c[d]; s += v * v; }
    cbsq[k] = (float)s;
}

template <bool USE_WS>
__global__ __launch_bounds__(256, 2) void vq_argmin_kernel(
    const float* __restrict__ z_e,
    const float* __restrict__ cb,
    const float* __restrict__ cbsq_ws,   // valid iff USE_WS
    float* __restrict__ out,             // [N*D] z_q, then [N] indices (as float)
    int N, int K)
{
    __shared__ float s_cbsq[VQ_MAXK];    // used only if !USE_WS (8KB/CU, harmless)

    if (!USE_WS) {
        for (int k = threadIdx.x; k < K; k += blockDim.x) {
            const float* c = cb + (size_t)k * VQ_D;
            double s = 0.0;
            #pragma unroll
            for (int d = 0; d < VQ_D; ++d) { double v = (double)c[d]; s += v * v; }
            s_cbsq[k] = (float)s;
        }
        __syncthreads();
    }

    // Two rows per thread: n0 = b*512 + t, n1 = n0 + 256.
    int n0 = blockIdx.x * (2 * (int)blockDim.x) + threadIdx.x;
    if (n0 >= N) return;                 // after the (optional) barrier: legal
    int n1 = n0 + (int)blockDim.x;
    if (n1 >= N) n1 = n0;                // harmless duplicate; never hit here

    // Both z rows in 32 NAMED float4 registers (NOT arrays — scratch hazard).
    const float4* zp0 = (const float4*)(z_e + (size_t)n0 * VQ_D);
    const float4* zp1 = (const float4*)(z_e + (size_t)n1 * VQ_D);
    float4 a0  = zp0[0],  a1  = zp0[1],  a2  = zp0[2],  a3  = zp0[3];
    float4 a4  = zp0[4],  a5  = zp0[5],  a6  = zp0[6],  a7  = zp0[7];
    float4 a8  = zp0[8],  a9  = zp0[9],  a10 = zp0[10], a11 = zp0[11];
    float4 a12 = zp0[12], a13 = zp0[13], a14 = zp0[14], a15 = zp0[15];
    float4 b0  = zp1[0],  b1  = zp1[1],  b2  = zp1[2],  b3  = zp1[3];
    float4 b4  = zp1[4],  b5  = zp1[5],  b6  = zp1[6],  b7  = zp1[7];
    float4 b8  = zp1[8],  b9  = zp1[9],  b10 = zp1[10], b11 = zp1[11];
    float4 b12 = zp1[12], b13 = zp1[13], b14 = zp1[14], b15 = zp1[15];

    // ||z||^2 in f64, rounded once (per row).
    double zs0 = 0.0, zs1 = 0.0;
    VQ_SQ(zs0, a0);  VQ_SQ(zs0, a1);  VQ_SQ(zs0, a2);  VQ_SQ(zs0, a3);
    VQ_SQ(zs0, a4);  VQ_SQ(zs0, a5);  VQ_SQ(zs0, a6);  VQ_SQ(zs0, a7);
    VQ_SQ(zs0, a8);  VQ_SQ(zs0, a9);  VQ_SQ(zs0, a10); VQ_SQ(zs0, a11);
    VQ_SQ(zs0, a12); VQ_SQ(zs0, a13); VQ_SQ(zs0, a14); VQ_SQ(zs0, a15);
    VQ_SQ(zs1, b0);  VQ_SQ(zs1, b1);  VQ_SQ(zs1, b2);  VQ_SQ(zs1, b3);
    VQ_SQ(zs1, b4);  VQ_SQ(zs1, b5);  VQ_SQ(zs1, b6);  VQ_SQ(zs1, b7);
    VQ_SQ(zs1, b8);  VQ_SQ(zs1, b9);  VQ_SQ(zs1, b10); VQ_SQ(zs1, b11);
    VQ_SQ(zs1, b12); VQ_SQ(zs1, b13); VQ_SQ(zs1, b14); VQ_SQ(zs1, b15);
    const float zsq0 = (float)zs0;
    const float zsq1 = (float)zs1;

    // Constant-AS views -> uniform loads become s_load (SGPR-resident rows).
    cb4c_t cbc = (cb4c_t)(unsigned long long)cb;      // 16 f4 per row
    fc_t   sqc = (fc_t)(unsigned long long)cbsq_ws;

    float best0 = 3.4e38f, best1 = 3.4e38f;
    int bk0 = 0, bk1 = 0;

    // Half-row ping-pong buffers (SGPR f4s). X = d0..31, Y = d32..63.
    f4 X0, X1, X2, X3, X4, X5, X6, X7;
    f4 Y0, Y1, Y2, Y3, Y4, Y5, Y6, Y7;
    float cq;

    // Prologue: issue A(0) into X. (One-time short-distance wait at k=0.)
    X0 = cbc[0]; X1 = cbc[1]; X2 = cbc[2]; X3 = cbc[3];
    X4 = cbc[4]; X5 = cbc[5]; X6 = cbc[6]; X7 = cbc[7];

    #pragma unroll 1
    for (int k = 0; k < K; ++k) {
        const int kb = k << 4;
        float s0 = 0.f, s1 = 0.f;

        // First X use: lgkmcnt(0) lands HERE, draining X issued mid-B-block of
        // the previous iteration (~450+ wave-cyc ago).
        VQ_CH2(a0, b0, X0);
        SBAR();
        // Issue box: B(k) -> Y, plus cbsq(k). Boxed so the scheduler can
        // neither hoist these above the X-wait nor sink them toward their use.
        Y0 = cbc[kb + 8];  Y1 = cbc[kb + 9];  Y2 = cbc[kb + 10]; Y3 = cbc[kb + 11];
        Y4 = cbc[kb + 12]; Y5 = cbc[kb + 13]; Y6 = cbc[kb + 14]; Y7 = cbc[kb + 15];
        cq = USE_WS ? sqc[k] : s_cbsq[k];
        SBAR();
        // Rest of A-half (d4..31), sequential ascending d.
        VQ_CH2(a1, b1, X1); VQ_CH2(a2, b2, X2); VQ_CH2(a3, b3, X3);
        VQ_CH2(a4, b4, X4); VQ_CH2(a5, b5, X5); VQ_CH2(a6, b6, X6);
        VQ_CH2(a7, b7, X7);

        // First Y use: lgkmcnt(0) lands HERE, draining Y+cq (issued ~7 CH2
        // groups ago). Nothing else is outstanding at this point by design.
        VQ_CH2(a8, b8, Y0);
        SBAR();
        // Issue box: A(k+1) -> X (clamped last iter; 64B reload, harmless).
        {
            int nk = k + 1; if (nk >= K) nk = K - 1;
            const int nb = nk << 4;
            X0 = cbc[nb + 0]; X1 = cbc[nb + 1]; X2 = cbc[nb + 2]; X3 = cbc[nb + 3];
            X4 = cbc[nb + 4]; X5 = cbc[nb + 5]; X6 = cbc[nb + 6]; X7 = cbc[nb + 7];
        }
        SBAR();
        // Rest of B-half (d36..63), sequential ascending d.
        VQ_CH2(a9,  b9,  Y1); VQ_CH2(a10, b10, Y2); VQ_CH2(a11, b11, Y3);
        VQ_CH2(a12, b12, Y4); VQ_CH2(a13, b13, Y5); VQ_CH2(a14, b14, Y6);
        VQ_CH2(a15, b15, Y7);

        // cq completed at the Y-wait; no further lgkm wait needed here.
        const float u0    = zsq0 - 2.0f * s0;   // 2*s exact; one fp32 round
        const float dist0 = u0 + cq;            // fp32 round, as reference
        const float u1    = zsq1 - 2.0f * s1;
        const float dist1 = u1 + cq;
        if (dist0 < best0) { best0 = dist0; bk0 = k; }  // strict <: lowest k
        if (dist1 < best1) { best1 = dist1; bk1 = k; }
    }

    // z_q gathers (divergent index -> per-lane VMEM; codebook L2-resident).
    {
        const float4* cq0 = (const float4*)(cb + (size_t)bk0 * VQ_D);
        float4* oq0 = (float4*)(out + (size_t)n0 * VQ_D);
        #pragma unroll
        for (int i = 0; i < VQ_D / 4; ++i) oq0[i] = cq0[i];
        const float4* cq1 = (const float4*)(cb + (size_t)bk1 * VQ_D);
        float4* oq1 = (float4*)(out + (size_t)n1 * VQ_D);
        #pragma unroll
        for (int i = 0; i < VQ_D / 4; ++i) oq1[i] = cq1[i];
    }

    // Indices as float (exact for k < 2^24).
    out[(size_t)N * VQ_D + n0] = (float)bk0;
    out[(size_t)N * VQ_D + n1] = (float)bk1;
}

extern "C" void kernel_launch(void* const* d_in, const int* in_sizes, int n_in,
                              void* d_out, int out_size, void* d_ws, size_t ws_size,
                              hipStream_t stream) {
    const float* z_e = (const float*)d_in[0];
    const float* cb  = (const float*)d_in[1];
    float* out = (float*)d_out;

    const int N = in_sizes[0] / VQ_D;
    const int K = in_sizes[1] / VQ_D;

    const int block = 256;
    const int rows_per_block = 2 * block;
    const int grid = (N + rows_per_block - 1) / rows_per_block;

    const bool use_ws = (d_ws != nullptr) && (ws_size >= (size_t)K * sizeof(float));
    if (use_ws) {
        float* cbsq = (float*)d_ws;
        vq_cbsq_kernel<<<(K + 255) / 256, 256, 0, stream>>>(cb, cbsq, K);
        vq_argmin_kernel<true><<<grid, block, 0, stream>>>(z_e, cb, cbsq, out, N, K);
    } else {
        vq_argmin_kernel<false><<<grid, block, 0, stream>>>(z_e, cb, nullptr, out, N, K);
    }
}